// Round 7
// baseline (280.047 us; speedup 1.0000x reference)
//
#include <hip/hip_runtime.h>
#include <hip/hip_bf16.h>

// Submanifold sparse conv 3x3x3, G=128, Cin=Cout=32.
// R7: no feats pre-conversion (the 96MB streaming pass cost ~100us of the
// 256us total). Conv gathers fp32 rows (2x float4) and converts to bf16
// in-register via packed cvt. W^T bf16 in LDS, stored in lane-consecutive
// fragment order [k][half][quad][co] -> ds_read_b128 conflict-free.
// M=16/wave, all 27 table lookups precomputed (MLP), 1024-thr blocks.

#define GRID 128
#define CIN 32
#define COUT 32
#define NOFF 27

typedef __attribute__((ext_vector_type(8))) short bf16x8;
typedef __attribute__((ext_vector_type(4))) float f32x4;

__device__ inline unsigned short f2bf(float x) {
    union { float f; unsigned u; } v; v.f = x;
    unsigned r = v.u + 0x7fff + ((v.u >> 16) & 1);   // RTNE
    return (unsigned short)(r >> 16);
}

// Prep: pos scatter (i<N) + wt [27][ci][co] fp32 -> bf16 in MFMA-fragment
// order: ushort idx = k*1024 + (co>>4)*512 + (ci>>3)*128 + (co&15)*8 + (ci&7).
// Lane (m,quad) of the conv wave then reads chunk (quad*16+m) consecutively.
__global__ void prep_kernel(const int* __restrict__ pos,
                            const float* __restrict__ wt,
                            int* __restrict__ table,
                            unsigned short* __restrict__ wtT, int N) {
    int i = blockIdx.x * 256 + threadIdx.x;
    if (i < N) {
        int x = pos[3 * i], y = pos[3 * i + 1], z = pos[3 * i + 2];
        // numpy duplicate semantics: last write (max index) wins
        atomicMax(&table[(x * GRID + y) * GRID + z], i);
    }
    if (i < NOFF * CIN * COUT) {
        int k = i >> 10, r = i & 1023, ci = r >> 5, co = r & 31;
        int idx = k * 1024 + (co >> 4) * 512 + (ci >> 3) * 128 + (co & 15) * 8 + (ci & 7);
        wtT[idx] = f2bf(wt[i]);
    }
}

__global__ __launch_bounds__(1024, 8)
void conv_kernel(const float* __restrict__ feats,
                 const int* __restrict__ pos,
                 const unsigned short* __restrict__ wtT,
                 const int* __restrict__ table,
                 float* __restrict__ out, int N) {
    __shared__ __align__(16) unsigned short ldsw[NOFF * 1024]; // 55296 B

    int tid = threadIdx.x;
    int wave = tid >> 6, lane = tid & 63;
    int m = lane & 15, quad = lane >> 4;
    int tile = blockIdx.x * 16 + wave;
    int base = tile * 16;
    int g = base + m;
    bool gv = g < N;                 // also false for tiles past the end

    int x = 0, y = 0, z = 0;
    if (gv) { x = pos[3 * g]; y = pos[3 * g + 1]; z = pos[3 * g + 2]; }
    int h = (x * GRID + y) * GRID + z;
    bool v0[3] = {gv && x > 0, gv, gv && x < GRID - 1};
    bool v1[3] = {gv && y > 0, gv, gv && y < GRID - 1};
    bool v2[3] = {gv && z > 0, gv, gv && z < GRID - 1};

    // Phase A: all 27 table lookups as independent loads (MLP).
    int ids[NOFF];
#pragma unroll
    for (int k = 0; k < NOFF; ++k) {
        const int dx = k / 9, dy = (k / 3) % 3, dz = k % 3;   // 0..2
        bool ok = v0[dx] && v1[dy] && v2[dz];
        int hk = h + (dx - 1) * GRID * GRID + (dy - 1) * GRID + (dz - 1);
        hk = ok ? hk : 0;
        int id = table[hk];
        ids[k] = ok ? id : -1;
    }

    // Stage W^T into LDS (already in fragment order -> contiguous copy).
    {
        const uint4* src = (const uint4*)wtT;    // 3456 x 16B
        uint4* dst = (uint4*)ldsw;
        for (int e = tid; e < NOFF * 1024 * 2 / 16; e += 1024)
            dst[e] = src[e];
    }
    __syncthreads();

    f32x4 acc0 = {0.f, 0.f, 0.f, 0.f};
    f32x4 acc1 = {0.f, 0.f, 0.f, 0.f};
    // lane-consecutive fragment chunks: byte = k*2048 + half*1024 + lane*16
    const unsigned short* wb = ldsw + (quad * 16 + m) * 8;

#pragma unroll
    for (int k = 0; k < NOFF; ++k) {
        int id = ids[k];
        int row = (id >= 0 ? id : 0) * CIN;
        const float* f = feats + (size_t)row + quad * 8;
        float4 f0 = *(const float4*)f;
        float4 f1 = *(const float4*)(f + 4);

        union { bf16x8 v; __hip_bfloat162 h2[4]; } a;
        a.h2[0] = __float22bfloat162_rn(make_float2(f0.x, f0.y));
        a.h2[1] = __float22bfloat162_rn(make_float2(f0.z, f0.w));
        a.h2[2] = __float22bfloat162_rn(make_float2(f1.x, f1.y));
        a.h2[3] = __float22bfloat162_rn(make_float2(f1.z, f1.w));
        if (id < 0) a.v = (bf16x8){0, 0, 0, 0, 0, 0, 0, 0};

        bf16x8 b0 = *(const bf16x8*)(wb + k * 1024);        // co = m
        bf16x8 b1 = *(const bf16x8*)(wb + k * 1024 + 512);  // co = m+16

        acc0 = __builtin_amdgcn_mfma_f32_16x16x32_bf16(a.v, b0, acc0, 0, 0, 0);
        acc1 = __builtin_amdgcn_mfma_f32_16x16x32_bf16(a.v, b1, acc1, 0, 0, 0);
    }

    // D layout: col = lane&15 = co, row = quad*4 + i = point within tile
#pragma unroll
    for (int i = 0; i < 4; ++i) {
        int p = base + quad * 4 + i;
        if (p < N) {
            out[(size_t)p * COUT + m]      = acc0[i];
            out[(size_t)p * COUT + m + 16] = acc1[i];
        }
    }
}

extern "C" void kernel_launch(void* const* d_in, const int* in_sizes, int n_in,
                              void* d_out, int out_size, void* d_ws, size_t ws_size,
                              hipStream_t stream) {
    const float* feats = (const float*)d_in[0];   // [N, 32]
    const int*   pos   = (const int*)d_in[1];     // [N, 3]
    const float* wt    = (const float*)d_in[2];   // [27, 32, 32]
    float* out = (float*)d_out;                   // [N, 32]
    int N = in_sizes[0] / CIN;

    char* ws = (char*)d_ws;
    int* table = (int*)ws;                                      // 8 MB
    size_t table_bytes = (size_t)GRID * GRID * GRID * sizeof(int);
    unsigned short* wtT = (unsigned short*)(ws + table_bytes);  // 55296 B

    hipMemsetAsync(table, 0xFF, table_bytes, stream);

    int pthreads = (N > NOFF * CIN * COUT) ? N : NOFF * CIN * COUT;
    prep_kernel<<<(pthreads + 255) / 256, 256, 0, stream>>>(pos, wt, table, wtT, N);

    int numTiles = (N + 15) / 16;
    int blocks = (numTiles + 15) / 16;   // 16 waves (1024 threads) per block
    conv_kernel<<<blocks, 1024, 0, stream>>>(feats, pos, wtT, table, out, N);
}